// Round 5
// baseline (460.568 us; speedup 1.0000x reference)
//
#include <hip/hip_runtime.h>

#define N_NODES 200000
#define N_EDGES 6400000
#define N_GRAPHS 2000
#define NBUCK 782          // ceil(200000/256) buckets of 256 dst nodes
#define CAP 10240          // per-bucket col capacity = 8 * CAP8
#define CAP8 1280          // per-(bucket,xcd-group) capacity (mean 1027, +7.9 sigma)
#define CHUNK 8192         // edges per partition block

// gcur[b*8+g] cursors, one per (bucket, xcd-group); region base = (b*8+g)*CAP8
__global__ __launch_bounds__(256) void init_cursor(int* __restrict__ gcur) {
  int i = blockIdx.x * 256 + threadIdx.x;
  if (i < NBUCK * 8) gcur[i] = i * CAP8;
}

// pass 1: per-block LDS histogram over buckets -> reservation in this block's
// XCD-group sub-region (g = blockIdx&7; round-robin block->XCD makes writes L2-local)
__global__ __launch_bounds__(256) void partition_kernel(
    const int* __restrict__ src, const int* __restrict__ dst,
    int* __restrict__ gcur, int* __restrict__ col) {
  __shared__ int cnt[NBUCK];
  __shared__ int base[NBUCK];
  int t = threadIdx.x;
  int g = blockIdx.x & 7;
  for (int b = t; b < NBUCK; b += 256) cnt[b] = 0;
  __syncthreads();
  long e0 = (long)blockIdx.x * CHUNK;
  for (int i = t; i < CHUNK; i += 256) {
    long e = e0 + i;
    if (e < N_EDGES) atomicAdd(&cnt[dst[e] >> 8], 1);
  }
  __syncthreads();
  for (int b = t; b < NBUCK; b += 256) {
    int c = cnt[b];
    base[b] = c ? atomicAdd(&gcur[b * 8 + g], c) : 0;
    cnt[b] = 0;  // reuse as local cursor
  }
  __syncthreads();
  for (int i = t; i < CHUNK; i += 256) {
    long e = e0 + i;
    if (e < N_EDGES) {
      int d = dst[e];
      int b = d >> 8;
      int pos = base[b] + atomicAdd(&cnt[b], 1);
      if (pos < (b * 8 + g + 1) * CAP8)  // 7.9-sigma guard, never taken
        col[pos] = (src[e] << 8) | (d & 255);
    }
  }
}

// pass 2: stage bucket's 8 sub-regions to LDS, counting-sort by dst-local,
// write sorted src-only back IN-PLACE over the bucket's span [b*CAP, (b+1)*CAP).
__global__ __launch_bounds__(256) void sort_bucket(
    const int* __restrict__ gcur, int* __restrict__ col,
    int* __restrict__ rowstart, int* __restrict__ rowcnt) {
  __shared__ int sEdge[CAP];      // 40 KB staging
  __shared__ int hist[256], sc[256], lcur[256];
  int t = threadIdx.x;
  int b = blockIdx.x;
  hist[t] = 0;
  __syncthreads();
  int total = 0;
  for (int g = 0; g < 8; g++) {
    int beg = (b * 8 + g) * CAP8;
    int cg = gcur[b * 8 + g] - beg;
    if (cg > CAP8) cg = CAP8;
    for (int i = t; i < cg; i += 256) {
      int p = col[beg + i];
      sEdge[total + i] = p;
      atomicAdd(&hist[p & 255], 1);
    }
    total += cg;
  }
  __syncthreads();
  // exclusive scan of hist -> sc
  sc[t] = hist[t];
  __syncthreads();
  for (int off = 1; off < 256; off <<= 1) {
    int v = (t >= off) ? sc[t - off] : 0;
    __syncthreads();
    sc[t] += v;
    __syncthreads();
  }
  int excl = sc[t] - hist[t];
  lcur[t] = excl;
  int n = b * 256 + t;
  if (n < N_NODES) {
    rowstart[n] = b * CAP + excl;
    rowcnt[n] = hist[t];
  }
  __syncthreads();
  for (int i = t; i < total; i += 256) {
    int p = sEdge[i];
    int pos = atomicAdd(&lcur[p & 255], 1);
    col[b * CAP + pos] = p >> 8;  // src only, grouped by dst-local
  }
}

// ---------- layer 1 aggregation: one wave per node, dim 2 ----------
__global__ __launch_bounds__(256) void aggr2_wave(
    const int* __restrict__ rowstart, const int* __restrict__ rowcnt,
    const int* __restrict__ col, const float* __restrict__ x,
    float* __restrict__ agg) {
  int n = blockIdx.x * 4 + (threadIdx.x >> 6);  // 200000 = 50000*4 exactly
  int lane = threadIdx.x & 63;
  int e0 = rowstart[n], c = rowcnt[n];
  float a0 = 0.f, a1 = 0.f;
  for (int basei = 0; basei < c; basei += 64) {
    int idx = basei + lane;
    if (idx < c) {
      int s = col[e0 + idx];
      float2 u = *reinterpret_cast<const float2*>(x + 2 * s);
      a0 += u.x; a1 += u.y;
    }
  }
#pragma unroll
  for (int off = 1; off <= 32; off <<= 1) {
    a0 += __shfl_xor(a0, off, 64);
    a1 += __shfl_xor(a1, off, 64);
  }
  if (lane == 0) {
    *reinterpret_cast<float2*>(agg + 2 * n) = make_float2(a0, a1);
  }
}

// ---------- layers 2/3 aggregation: one wave per node, dim 16 ----------
__global__ __launch_bounds__(256) void aggr16_wave(
    const int* __restrict__ rowstart, const int* __restrict__ rowcnt,
    const int* __restrict__ col, const float* __restrict__ h,
    float* __restrict__ agg) {
  int n = blockIdx.x * 4 + (threadIdx.x >> 6);
  int lane = threadIdx.x & 63;
  int e0 = rowstart[n], c = rowcnt[n];
  float a[8];
#pragma unroll
  for (int j = 0; j < 8; j++) a[j] = 0.f;
  int half = lane & 1;
  for (int basei = 0; basei < c; basei += 32) {
    int idx = basei + (lane >> 1);
    if (idx < c) {
      int s = col[e0 + idx];
      const float4* p = reinterpret_cast<const float4*>(h + 16 * s + 8 * half);
      float4 u = p[0], v = p[1];
      a[0] += u.x; a[1] += u.y; a[2] += u.z; a[3] += u.w;
      a[4] += v.x; a[5] += v.y; a[6] += v.z; a[7] += v.w;
    }
  }
#pragma unroll
  for (int off = 2; off <= 32; off <<= 1) {
#pragma unroll
    for (int j = 0; j < 8; j++) a[j] += __shfl_xor(a[j], off, 64);
  }
  if (lane < 2) {
    float* dstp = agg + n * 16 + 8 * lane;
    *reinterpret_cast<float4*>(dstp) = make_float4(a[0], a[1], a[2], a[3]);
    *reinterpret_cast<float4*>(dstp + 4) = make_float4(a[4], a[5], a[6], a[7]);
  }
}

// ---------- layer 1 node MLP (2 -> 16 -> 16), outer relu ----------
__global__ __launch_bounds__(256) void node_l1(
    const float* __restrict__ x, const float* __restrict__ aggr,
    const float* __restrict__ Wa, const float* __restrict__ ba,
    const float* __restrict__ Wb, const float* __restrict__ bb,
    float* __restrict__ out) {
  __shared__ float sWa[32], sba[16], sWb[256], sbb[16];
  int t = threadIdx.x;
  if (t < 32) sWa[t] = Wa[t];
  if (t < 16) { sba[t] = ba[t]; sbb[t] = bb[t]; }
  for (int i = t; i < 256; i += 256) sWb[i] = Wb[i];
  __syncthreads();
  int n = blockIdx.x * blockDim.x + t;
  if (n >= N_NODES) return;
  float2 xv = *reinterpret_cast<const float2*>(x + 2 * n);
  float2 av = *reinterpret_cast<const float2*>(aggr + 2 * n);
  float v0 = xv.x + av.x, v1 = xv.y + av.y;
  float h1[16];
#pragma unroll
  for (int j = 0; j < 16; j++)
    h1[j] = fmaxf(fmaf(v0, sWa[j], fmaf(v1, sWa[16 + j], sba[j])), 0.f);
  float o[16];
#pragma unroll
  for (int j = 0; j < 16; j++) {
    float s = sbb[j];
#pragma unroll
    for (int k = 0; k < 16; k++) s = fmaf(h1[k], sWb[k * 16 + j], s);
    o[j] = fmaxf(s, 0.f);
  }
  float4* op = reinterpret_cast<float4*>(out + n * 16);
#pragma unroll
  for (int q = 0; q < 4; q++)
    op[q] = make_float4(o[4 * q], o[4 * q + 1], o[4 * q + 2], o[4 * q + 3]);
}

// ---------- layers 2/3 node MLP (16 -> 16 -> 16), outer relu ----------
__global__ __launch_bounds__(256) void node16(
    const float* __restrict__ hin, const float* __restrict__ aggr,
    const float* __restrict__ Wa, const float* __restrict__ ba,
    const float* __restrict__ Wb, const float* __restrict__ bb,
    float* __restrict__ out) {
  __shared__ float sWa[256], sba[16], sWb[256], sbb[16];
  int t = threadIdx.x;
  if (t < 16) { sba[t] = ba[t]; sbb[t] = bb[t]; }
  for (int i = t; i < 256; i += 256) { sWa[i] = Wa[i]; sWb[i] = Wb[i]; }
  __syncthreads();
  int n = blockIdx.x * blockDim.x + t;
  if (n >= N_NODES) return;
  float v[16];
  const float4* hp = reinterpret_cast<const float4*>(hin + 16 * n);
  const float4* ap = reinterpret_cast<const float4*>(aggr + 16 * n);
#pragma unroll
  for (int q = 0; q < 4; q++) {
    float4 hv = hp[q], av = ap[q];
    v[4 * q + 0] = hv.x + av.x; v[4 * q + 1] = hv.y + av.y;
    v[4 * q + 2] = hv.z + av.z; v[4 * q + 3] = hv.w + av.w;
  }
  float h1[16];
#pragma unroll
  for (int j = 0; j < 16; j++) {
    float s = sba[j];
#pragma unroll
    for (int k = 0; k < 16; k++) s = fmaf(v[k], sWa[k * 16 + j], s);
    h1[j] = fmaxf(s, 0.f);
  }
  float o[16];
#pragma unroll
  for (int j = 0; j < 16; j++) {
    float s = sbb[j];
#pragma unroll
    for (int k = 0; k < 16; k++) s = fmaf(h1[k], sWb[k * 16 + j], s);
    o[j] = fmaxf(s, 0.f);
  }
  float4* op = reinterpret_cast<float4*>(out + n * 16);
#pragma unroll
  for (int q = 0; q < 4; q++)
    op[q] = make_float4(o[4 * q], o[4 * q + 1], o[4 * q + 2], o[4 * q + 3]);
}

// ---------- pool: one 64-lane block per graph; batch is sorted ----------
__global__ __launch_bounds__(64) void pool_kernel(
    const float* __restrict__ h, const int* __restrict__ batch,
    float* __restrict__ g) {
  int gr = blockIdx.x;
  int lo = 0, hi = N_NODES;
  while (lo < hi) { int mid = (lo + hi) >> 1; if (batch[mid] < gr) lo = mid + 1; else hi = mid; }
  int start = lo;
  hi = N_NODES;
  while (lo < hi) { int mid = (lo + hi) >> 1; if (batch[mid] < gr + 1) lo = mid + 1; else hi = mid; }
  int end = lo;
  float acc[16];
#pragma unroll
  for (int j = 0; j < 16; j++) acc[j] = 0.f;
  for (int n = start + threadIdx.x; n < end; n += 64) {
    const float4* hp = reinterpret_cast<const float4*>(h + 16 * n);
#pragma unroll
    for (int q = 0; q < 4; q++) {
      float4 hv = hp[q];
      acc[4 * q + 0] += hv.x; acc[4 * q + 1] += hv.y;
      acc[4 * q + 2] += hv.z; acc[4 * q + 3] += hv.w;
    }
  }
#pragma unroll
  for (int j = 0; j < 16; j++) {
#pragma unroll
    for (int off = 32; off > 0; off >>= 1) acc[j] += __shfl_xor(acc[j], off, 64);
  }
  if (threadIdx.x == 0) {
    float4* gp = reinterpret_cast<float4*>(g + gr * 16);
#pragma unroll
    for (int q = 0; q < 4; q++)
      gp[q] = make_float4(acc[4 * q], acc[4 * q + 1], acc[4 * q + 2], acc[4 * q + 3]);
  }
}

// ---------- head: relu(g@Wl1+bl1)@Wl2+bl2 ----------
__global__ __launch_bounds__(256) void head_kernel(
    const float* __restrict__ g,
    const float* __restrict__ Wl1, const float* __restrict__ bl1,
    const float* __restrict__ Wl2, const float* __restrict__ bl2,
    float* __restrict__ out) {
  __shared__ float sW1[256], sb1[16], sW2[16];
  int t = threadIdx.x;
  if (t < 16) { sb1[t] = bl1[t]; sW2[t] = Wl2[t]; }
  for (int i = t; i < 256; i += 256) sW1[i] = Wl1[i];
  __syncthreads();
  int gr = blockIdx.x * blockDim.x + t;
  if (gr >= N_GRAPHS) return;
  float v[16];
  const float4* gp = reinterpret_cast<const float4*>(g + 16 * gr);
#pragma unroll
  for (int q = 0; q < 4; q++) {
    float4 gv = gp[q];
    v[4 * q + 0] = gv.x; v[4 * q + 1] = gv.y; v[4 * q + 2] = gv.z; v[4 * q + 3] = gv.w;
  }
  float o = bl2[0];
#pragma unroll
  for (int j = 0; j < 16; j++) {
    float s = sb1[j];
#pragma unroll
    for (int k = 0; k < 16; k++) s = fmaf(v[k], sW1[k * 16 + j], s);
    o = fmaf(fmaxf(s, 0.f), sW2[j], o);
  }
  out[gr] = o;
}

extern "C" void kernel_launch(void* const* d_in, const int* in_sizes, int n_in,
                              void* d_out, int out_size, void* d_ws, size_t ws_size,
                              hipStream_t stream) {
  const float* x     = (const float*)d_in[0];
  const int*   ei    = (const int*)d_in[1];
  const int*   src   = ei;
  const int*   dst   = ei + N_EDGES;
  const int*   batch = (const int*)d_in[2];
  const float* W1a = (const float*)d_in[3];  const float* b1a = (const float*)d_in[4];
  const float* W1b = (const float*)d_in[5];  const float* b1b = (const float*)d_in[6];
  const float* W2a = (const float*)d_in[7];  const float* b2a = (const float*)d_in[8];
  const float* W2b = (const float*)d_in[9];  const float* b2b = (const float*)d_in[10];
  const float* W3a = (const float*)d_in[11]; const float* b3a = (const float*)d_in[12];
  const float* W3b = (const float*)d_in[13]; const float* b3b = (const float*)d_in[14];
  const float* Wl1 = (const float*)d_in[15]; const float* bl1 = (const float*)d_in[16];
  const float* Wl2 = (const float*)d_in[17]; const float* bl2 = (const float*)d_in[18];
  float* out = (float*)d_out;

  // ws layout
  int*   gcur     = (int*)d_ws;                         // NBUCK*8 (padded 6400)
  int*   col      = gcur + 6400;                        // NBUCK*CAP packed/sorted edges
  int*   rowstart = col + (size_t)NBUCK * CAP;          // N_NODES (padded)
  int*   rowcnt   = rowstart + 200192;                  // N_NODES (padded)
  float* agg      = (float*)(rowcnt + 200192);          // N_NODES*16
  float* hA       = agg + (size_t)N_NODES * 16;         // N_NODES*16
  float* hB       = hA + (size_t)N_NODES * 16;          // N_NODES*16
  float* g        = hB + (size_t)N_NODES * 16;          // N_GRAPHS*16

  const int PBLK = (N_EDGES + CHUNK - 1) / CHUNK;       // 782
  const int NWAVE_BLK = N_NODES / 4;                    // 50000 (exact)
  dim3 ngrid((N_NODES + 255) / 256);

  init_cursor<<<(NBUCK * 8 + 255) / 256, 256, 0, stream>>>(gcur);
  partition_kernel<<<PBLK, 256, 0, stream>>>(src, dst, gcur, col);
  sort_bucket<<<NBUCK, 256, 0, stream>>>(gcur, col, rowstart, rowcnt);

  // layer 1
  aggr2_wave<<<NWAVE_BLK, 256, 0, stream>>>(rowstart, rowcnt, col, x, agg);
  node_l1<<<ngrid, 256, 0, stream>>>(x, agg, W1a, b1a, W1b, b1b, hA);
  // layer 2
  aggr16_wave<<<NWAVE_BLK, 256, 0, stream>>>(rowstart, rowcnt, col, hA, agg);
  node16<<<ngrid, 256, 0, stream>>>(hA, agg, W2a, b2a, W2b, b2b, hB);
  // layer 3
  aggr16_wave<<<NWAVE_BLK, 256, 0, stream>>>(rowstart, rowcnt, col, hB, agg);
  node16<<<ngrid, 256, 0, stream>>>(hB, agg, W3a, b3a, W3b, b3b, hA);

  pool_kernel<<<N_GRAPHS, 64, 0, stream>>>(hA, batch, g);
  head_kernel<<<(N_GRAPHS + 255) / 256, 256, 0, stream>>>(g, Wl1, bl1, Wl2, bl2, out);
}

// Round 6
// 397.271 us; speedup vs baseline: 1.1593x; 1.1593x over previous
//
#include <hip/hip_runtime.h>

#define N_NODES 200000
#define N_EDGES 6400000
#define N_GRAPHS 2000

// level-1: megabuckets of 2048 dst nodes
#define MBSHIFT 11
#define NMB 98             // ceil(200000/2048)
#define MBCAP 67584        // mean 65536 + 8 sigma
#define CHUNK 8192         // edges per partA block
#define PBLK 782           // ceil(6.4M/8192)
#define PB 9               // partB blocks per megabucket (9*8192 >= MBCAP)

// level-2: fine buckets of 128 dst nodes
#define FSHIFT 7
#define NBUCK 1563         // ceil(200000/128)
#define CAPF 4608          // mean 4096 + 8 sigma

__global__ __launch_bounds__(256) void init_cursors(int* __restrict__ gcurA,
                                                    int* __restrict__ gcur2) {
  int i = blockIdx.x * 256 + threadIdx.x;
  if (i < NMB) gcurA[i] = i * MBCAP;
  if (i < NMB * 16) gcur2[i] = i * CAPF;
}

// pass A: chunk -> LDS counting sort by megabucket -> contiguous per-bin copy-out
__global__ __launch_bounds__(256) void partA(
    const int* __restrict__ src, const int* __restrict__ dst,
    int* __restrict__ gcurA, int* __restrict__ colA) {
  __shared__ int hist[NMB], base[NMB], lcur[NMB], excl[NMB];
  __shared__ int sc[128];
  __shared__ int sorted[CHUNK];  // 32 KB
  int t = threadIdx.x;
  for (int i = t; i < NMB; i += 256) hist[i] = 0;
  __syncthreads();
  int e0 = blockIdx.x * CHUNK;
  int cnt = N_EDGES - e0; if (cnt > CHUNK) cnt = CHUNK;
  for (int i = t; i < cnt; i += 256) atomicAdd(&hist[dst[e0 + i] >> MBSHIFT], 1);
  __syncthreads();
  if (t < 128) sc[t] = (t < NMB) ? hist[t] : 0;
  __syncthreads();
  for (int off = 1; off < 128; off <<= 1) {
    int v = (t < 128 && t >= off) ? sc[t - off] : 0;
    __syncthreads();
    if (t < 128) sc[t] += v;
    __syncthreads();
  }
  if (t < NMB) {
    int e = sc[t] - hist[t];
    excl[t] = e; lcur[t] = e;
    base[t] = hist[t] ? atomicAdd(&gcurA[t], hist[t]) : 0;
  }
  __syncthreads();
  for (int i = t; i < cnt; i += 256) {
    int d = dst[e0 + i];
    int b = d >> MBSHIFT;
    int r = atomicAdd(&lcur[b], 1);
    sorted[r] = (src[e0 + i] << MBSHIFT) | (d & 2047);
  }
  __syncthreads();
  for (int b = 0; b < NMB; b++) {
    int c = hist[b], gb = base[b], lb = excl[b];
    int lim = (b + 1) * MBCAP;
    for (int i = t; i < c; i += 256) {
      int pos = gb + i;
      if (pos < lim) colA[pos] = sorted[lb + i];  // 8-sigma guard
    }
  }
}

// pass B: megabucket chunk -> LDS sort into 16 fine buckets -> coalesced copy-out
__global__ __launch_bounds__(256) void partB(
    const int* __restrict__ gcurA, const int* __restrict__ colA,
    int* __restrict__ gcur2, int* __restrict__ col) {
  __shared__ int hist[16], base[16], lcur[16], excl[16];
  __shared__ int sorted[CHUNK];  // 32 KB
  int t = threadIdx.x;
  int mb = blockIdx.x / PB, j = blockIdx.x % PB;
  int mbbase = mb * MBCAP;
  int mbcnt = gcurA[mb] - mbbase; if (mbcnt > MBCAP) mbcnt = MBCAP;
  int c0 = j * CHUNK;
  int cnt = mbcnt - c0;
  if (cnt > CHUNK) cnt = CHUNK;
  if (cnt < 0) cnt = 0;
  if (t < 16) hist[t] = 0;
  __syncthreads();
  const int* seg = colA + mbbase + c0;
  for (int i = t; i < cnt; i += 256) atomicAdd(&hist[(seg[i] & 2047) >> FSHIFT], 1);
  __syncthreads();
  if (t == 0) {
    int run = 0;
    for (int b = 0; b < 16; b++) { excl[b] = run; lcur[b] = run; run += hist[b]; }
  }
  if (t < 16) base[t] = hist[t] ? atomicAdd(&gcur2[mb * 16 + t], hist[t]) : 0;
  __syncthreads();
  for (int i = t; i < cnt; i += 256) {
    int p = seg[i];
    int b = (p & 2047) >> FSHIFT;
    int r = atomicAdd(&lcur[b], 1);
    sorted[r] = ((p >> MBSHIFT) << FSHIFT) | (p & 127);  // src<<7 | dst&127
  }
  __syncthreads();
  for (int b = 0; b < 16; b++) {
    int c = hist[b], gb = base[b], lb = excl[b];
    int lim = (mb * 16 + b + 1) * CAPF;
    for (int i = t; i < c; i += 256) {
      int pos = gb + i;
      if (pos < lim) col[pos] = sorted[lb + i];  // 8-sigma guard
    }
  }
}

// fine sort: 128-bin counting sort fully staged in LDS, linear coalesced write-back
__global__ __launch_bounds__(256) void sort_fine(
    const int* __restrict__ gcur2, int* __restrict__ col,
    int* __restrict__ rowstart, int* __restrict__ rowcnt) {
  __shared__ int hist[128], sc[128], lcur[128];
  __shared__ int sorted[CAPF];   // 18 KB
  int t = threadIdx.x;
  int fb = blockIdx.x;
  int beg = fb * CAPF;
  int cnt = gcur2[fb] - beg; if (cnt > CAPF) cnt = CAPF;
  if (t < 128) hist[t] = 0;
  __syncthreads();
  for (int i = t; i < cnt; i += 256) atomicAdd(&hist[col[beg + i] & 127], 1);
  __syncthreads();
  if (t < 128) sc[t] = hist[t];
  __syncthreads();
  for (int off = 1; off < 128; off <<= 1) {
    int v = (t < 128 && t >= off) ? sc[t - off] : 0;
    __syncthreads();
    if (t < 128) sc[t] += v;
    __syncthreads();
  }
  if (t < 128) {
    int excl = sc[t] - hist[t];
    lcur[t] = excl;
    int n = fb * 128 + t;
    if (n < N_NODES) { rowstart[n] = beg + excl; rowcnt[n] = hist[t]; }
  }
  __syncthreads();
  for (int i = t; i < cnt; i += 256) {
    int p = col[beg + i];
    int r = atomicAdd(&lcur[p & 127], 1);
    sorted[r] = p >> FSHIFT;   // src only, grouped by dst
  }
  __syncthreads();
  for (int i = t; i < cnt; i += 256) col[beg + i] = sorted[i];
}

// ---------- layer 1 aggregation: one wave per node, dim 2 ----------
__global__ __launch_bounds__(256) void aggr2_wave(
    const int* __restrict__ rowstart, const int* __restrict__ rowcnt,
    const int* __restrict__ col, const float* __restrict__ x,
    float* __restrict__ agg) {
  int n = blockIdx.x * 4 + (threadIdx.x >> 6);  // 200000 = 50000*4 exactly
  int lane = threadIdx.x & 63;
  int e0 = rowstart[n], c = rowcnt[n];
  float a0 = 0.f, a1 = 0.f;
  for (int basei = 0; basei < c; basei += 64) {
    int idx = basei + lane;
    if (idx < c) {
      int s = col[e0 + idx];
      float2 u = *reinterpret_cast<const float2*>(x + 2 * s);
      a0 += u.x; a1 += u.y;
    }
  }
#pragma unroll
  for (int off = 1; off <= 32; off <<= 1) {
    a0 += __shfl_xor(a0, off, 64);
    a1 += __shfl_xor(a1, off, 64);
  }
  if (lane == 0) {
    *reinterpret_cast<float2*>(agg + 2 * n) = make_float2(a0, a1);
  }
}

// ---------- layers 2/3 aggregation: one wave per node, dim 16 ----------
__global__ __launch_bounds__(256) void aggr16_wave(
    const int* __restrict__ rowstart, const int* __restrict__ rowcnt,
    const int* __restrict__ col, const float* __restrict__ h,
    float* __restrict__ agg) {
  int n = blockIdx.x * 4 + (threadIdx.x >> 6);
  int lane = threadIdx.x & 63;
  int e0 = rowstart[n], c = rowcnt[n];
  float a[8];
#pragma unroll
  for (int j = 0; j < 8; j++) a[j] = 0.f;
  int half = lane & 1;
  for (int basei = 0; basei < c; basei += 32) {
    int idx = basei + (lane >> 1);
    if (idx < c) {
      int s = col[e0 + idx];
      const float4* p = reinterpret_cast<const float4*>(h + 16 * s + 8 * half);
      float4 u = p[0], v = p[1];
      a[0] += u.x; a[1] += u.y; a[2] += u.z; a[3] += u.w;
      a[4] += v.x; a[5] += v.y; a[6] += v.z; a[7] += v.w;
    }
  }
#pragma unroll
  for (int off = 2; off <= 32; off <<= 1) {
#pragma unroll
    for (int j = 0; j < 8; j++) a[j] += __shfl_xor(a[j], off, 64);
  }
  if (lane < 2) {
    float* dstp = agg + n * 16 + 8 * lane;
    *reinterpret_cast<float4*>(dstp) = make_float4(a[0], a[1], a[2], a[3]);
    *reinterpret_cast<float4*>(dstp + 4) = make_float4(a[4], a[5], a[6], a[7]);
  }
}

// ---------- layer 1 node MLP (2 -> 16 -> 16), outer relu ----------
__global__ __launch_bounds__(256) void node_l1(
    const float* __restrict__ x, const float* __restrict__ aggr,
    const float* __restrict__ Wa, const float* __restrict__ ba,
    const float* __restrict__ Wb, const float* __restrict__ bb,
    float* __restrict__ out) {
  __shared__ float sWa[32], sba[16], sWb[256], sbb[16];
  int t = threadIdx.x;
  if (t < 32) sWa[t] = Wa[t];
  if (t < 16) { sba[t] = ba[t]; sbb[t] = bb[t]; }
  for (int i = t; i < 256; i += 256) sWb[i] = Wb[i];
  __syncthreads();
  int n = blockIdx.x * blockDim.x + t;
  if (n >= N_NODES) return;
  float2 xv = *reinterpret_cast<const float2*>(x + 2 * n);
  float2 av = *reinterpret_cast<const float2*>(aggr + 2 * n);
  float v0 = xv.x + av.x, v1 = xv.y + av.y;
  float h1[16];
#pragma unroll
  for (int j = 0; j < 16; j++)
    h1[j] = fmaxf(fmaf(v0, sWa[j], fmaf(v1, sWa[16 + j], sba[j])), 0.f);
  float o[16];
#pragma unroll
  for (int j = 0; j < 16; j++) {
    float s = sbb[j];
#pragma unroll
    for (int k = 0; k < 16; k++) s = fmaf(h1[k], sWb[k * 16 + j], s);
    o[j] = fmaxf(s, 0.f);
  }
  float4* op = reinterpret_cast<float4*>(out + n * 16);
#pragma unroll
  for (int q = 0; q < 4; q++)
    op[q] = make_float4(o[4 * q], o[4 * q + 1], o[4 * q + 2], o[4 * q + 3]);
}

// ---------- layers 2/3 node MLP (16 -> 16 -> 16), outer relu ----------
__global__ __launch_bounds__(256) void node16(
    const float* __restrict__ hin, const float* __restrict__ aggr,
    const float* __restrict__ Wa, const float* __restrict__ ba,
    const float* __restrict__ Wb, const float* __restrict__ bb,
    float* __restrict__ out) {
  __shared__ float sWa[256], sba[16], sWb[256], sbb[16];
  int t = threadIdx.x;
  if (t < 16) { sba[t] = ba[t]; sbb[t] = bb[t]; }
  for (int i = t; i < 256; i += 256) { sWa[i] = Wa[i]; sWb[i] = Wb[i]; }
  __syncthreads();
  int n = blockIdx.x * blockDim.x + t;
  if (n >= N_NODES) return;
  float v[16];
  const float4* hp = reinterpret_cast<const float4*>(hin + 16 * n);
  const float4* ap = reinterpret_cast<const float4*>(aggr + 16 * n);
#pragma unroll
  for (int q = 0; q < 4; q++) {
    float4 hv = hp[q], av = ap[q];
    v[4 * q + 0] = hv.x + av.x; v[4 * q + 1] = hv.y + av.y;
    v[4 * q + 2] = hv.z + av.z; v[4 * q + 3] = hv.w + av.w;
  }
  float h1[16];
#pragma unroll
  for (int j = 0; j < 16; j++) {
    float s = sba[j];
#pragma unroll
    for (int k = 0; k < 16; k++) s = fmaf(v[k], sWa[k * 16 + j], s);
    h1[j] = fmaxf(s, 0.f);
  }
  float o[16];
#pragma unroll
  for (int j = 0; j < 16; j++) {
    float s = sbb[j];
#pragma unroll
    for (int k = 0; k < 16; k++) s = fmaf(h1[k], sWb[k * 16 + j], s);
    o[j] = fmaxf(s, 0.f);
  }
  float4* op = reinterpret_cast<float4*>(out + n * 16);
#pragma unroll
  for (int q = 0; q < 4; q++)
    op[q] = make_float4(o[4 * q], o[4 * q + 1], o[4 * q + 2], o[4 * q + 3]);
}

// ---------- pool: one 64-lane block per graph; batch is sorted ----------
__global__ __launch_bounds__(64) void pool_kernel(
    const float* __restrict__ h, const int* __restrict__ batch,
    float* __restrict__ g) {
  int gr = blockIdx.x;
  int lo = 0, hi = N_NODES;
  while (lo < hi) { int mid = (lo + hi) >> 1; if (batch[mid] < gr) lo = mid + 1; else hi = mid; }
  int start = lo;
  hi = N_NODES;
  while (lo < hi) { int mid = (lo + hi) >> 1; if (batch[mid] < gr + 1) lo = mid + 1; else hi = mid; }
  int end = lo;
  float acc[16];
#pragma unroll
  for (int j = 0; j < 16; j++) acc[j] = 0.f;
  for (int n = start + threadIdx.x; n < end; n += 64) {
    const float4* hp = reinterpret_cast<const float4*>(h + 16 * n);
#pragma unroll
    for (int q = 0; q < 4; q++) {
      float4 hv = hp[q];
      acc[4 * q + 0] += hv.x; acc[4 * q + 1] += hv.y;
      acc[4 * q + 2] += hv.z; acc[4 * q + 3] += hv.w;
    }
  }
#pragma unroll
  for (int j = 0; j < 16; j++) {
#pragma unroll
    for (int off = 32; off > 0; off >>= 1) acc[j] += __shfl_xor(acc[j], off, 64);
  }
  if (threadIdx.x == 0) {
    float4* gp = reinterpret_cast<float4*>(g + gr * 16);
#pragma unroll
    for (int q = 0; q < 4; q++)
      gp[q] = make_float4(acc[4 * q], acc[4 * q + 1], acc[4 * q + 2], acc[4 * q + 3]);
  }
}

// ---------- head: relu(g@Wl1+bl1)@Wl2+bl2 ----------
__global__ __launch_bounds__(256) void head_kernel(
    const float* __restrict__ g,
    const float* __restrict__ Wl1, const float* __restrict__ bl1,
    const float* __restrict__ Wl2, const float* __restrict__ bl2,
    float* __restrict__ out) {
  __shared__ float sW1[256], sb1[16], sW2[16];
  int t = threadIdx.x;
  if (t < 16) { sb1[t] = bl1[t]; sW2[t] = Wl2[t]; }
  for (int i = t; i < 256; i += 256) sW1[i] = Wl1[i];
  __syncthreads();
  int gr = blockIdx.x * blockDim.x + t;
  if (gr >= N_GRAPHS) return;
  float v[16];
  const float4* gp = reinterpret_cast<const float4*>(g + 16 * gr);
#pragma unroll
  for (int q = 0; q < 4; q++) {
    float4 gv = gp[q];
    v[4 * q + 0] = gv.x; v[4 * q + 1] = gv.y; v[4 * q + 2] = gv.z; v[4 * q + 3] = gv.w;
  }
  float o = bl2[0];
#pragma unroll
  for (int j = 0; j < 16; j++) {
    float s = sb1[j];
#pragma unroll
    for (int k = 0; k < 16; k++) s = fmaf(v[k], sW1[k * 16 + j], s);
    o = fmaf(fmaxf(s, 0.f), sW2[j], o);
  }
  out[gr] = o;
}

extern "C" void kernel_launch(void* const* d_in, const int* in_sizes, int n_in,
                              void* d_out, int out_size, void* d_ws, size_t ws_size,
                              hipStream_t stream) {
  const float* x     = (const float*)d_in[0];
  const int*   ei    = (const int*)d_in[1];
  const int*   src   = ei;
  const int*   dst   = ei + N_EDGES;
  const int*   batch = (const int*)d_in[2];
  const float* W1a = (const float*)d_in[3];  const float* b1a = (const float*)d_in[4];
  const float* W1b = (const float*)d_in[5];  const float* b1b = (const float*)d_in[6];
  const float* W2a = (const float*)d_in[7];  const float* b2a = (const float*)d_in[8];
  const float* W2b = (const float*)d_in[9];  const float* b2b = (const float*)d_in[10];
  const float* W3a = (const float*)d_in[11]; const float* b3a = (const float*)d_in[12];
  const float* W3b = (const float*)d_in[13]; const float* b3b = (const float*)d_in[14];
  const float* Wl1 = (const float*)d_in[15]; const float* bl1 = (const float*)d_in[16];
  const float* Wl2 = (const float*)d_in[17]; const float* bl2 = (const float*)d_in[18];
  float* out = (float*)d_out;

  // ws layout (ints). colA is aliased over the layer buffers (dead after partB;
  // single-stream ordering makes the overlap safe and deterministic).
  int*   gcurA    = (int*)d_ws;                         // NMB (pad 128)
  int*   gcur2    = gcurA + 128;                        // NMB*16=1568 (pad 2048)
  int*   rowstart = gcur2 + 2048;                       // N_NODES (pad 200192)
  int*   rowcnt   = rowstart + 200192;                  // N_NODES (pad 200192)
  int*   col      = rowcnt + 200192;                    // NBUCK*CAPF = 7,202,304
  int*   U        = col + (size_t)NBUCK * CAPF;         // union region
  int*   colA     = U;                                  // NMB*MBCAP = 6,623,232 ints
  float* agg      = (float*)U;                          // N_NODES*16 (after partB)
  float* hA       = agg + (size_t)N_NODES * 16;
  float* hB       = hA + (size_t)N_NODES * 16;
  float* g        = hB + (size_t)N_NODES * 16;          // N_GRAPHS*16

  const int NWAVE_BLK = N_NODES / 4;                    // 50000 (exact)
  dim3 ngrid((N_NODES + 255) / 256);

  init_cursors<<<(NMB * 16 + 255) / 256, 256, 0, stream>>>(gcurA, gcur2);
  partA<<<PBLK, 256, 0, stream>>>(src, dst, gcurA, colA);
  partB<<<NMB * PB, 256, 0, stream>>>(gcurA, colA, gcur2, col);
  sort_fine<<<NBUCK, 256, 0, stream>>>(gcur2, col, rowstart, rowcnt);

  // layer 1
  aggr2_wave<<<NWAVE_BLK, 256, 0, stream>>>(rowstart, rowcnt, col, x, agg);
  node_l1<<<ngrid, 256, 0, stream>>>(x, agg, W1a, b1a, W1b, b1b, hA);
  // layer 2
  aggr16_wave<<<NWAVE_BLK, 256, 0, stream>>>(rowstart, rowcnt, col, hA, agg);
  node16<<<ngrid, 256, 0, stream>>>(hA, agg, W2a, b2a, W2b, b2b, hB);
  // layer 3
  aggr16_wave<<<NWAVE_BLK, 256, 0, stream>>>(rowstart, rowcnt, col, hB, agg);
  node16<<<ngrid, 256, 0, stream>>>(hB, agg, W3a, b3a, W3b, b3b, hA);

  pool_kernel<<<N_GRAPHS, 64, 0, stream>>>(hA, batch, g);
  head_kernel<<<(N_GRAPHS + 255) / 256, 256, 0, stream>>>(g, Wl1, bl1, Wl2, bl2, out);
}

// Round 7
// 373.935 us; speedup vs baseline: 1.2317x; 1.0624x over previous
//
#include <hip/hip_runtime.h>

#define N_NODES 200000
#define N_EDGES 6400000
#define N_GRAPHS 2000

// level-1: megabuckets of 2048 dst nodes
#define MBSHIFT 11
#define NMB 98             // ceil(200000/2048)
#define MBCAP 67584        // mean 65536 + 8 sigma
#define CHUNK 8192         // edges per partA block
#define PBLK 782           // ceil(6.4M/8192)
#define PB 9               // partB blocks per megabucket (9*8192 >= MBCAP)

// level-2: fine buckets of 128 dst nodes
#define FSHIFT 7
#define NBUCK 1563         // ceil(200000/128)
#define CAPF 4608          // mean 4096 + 8 sigma

// ---- bf16 helpers (storage = packed u16 pairs in uint; compute = f32) ----
__device__ __forceinline__ float bf_lo(unsigned v) { return __uint_as_float(v << 16); }
__device__ __forceinline__ float bf_hi(unsigned v) { return __uint_as_float(v & 0xFFFF0000u); }
__device__ __forceinline__ unsigned pack_bf2(float lo, float hi) {
  unsigned a = __float_as_uint(lo), b = __float_as_uint(hi);
  a = (a + 0x7FFFu + ((a >> 16) & 1u)) >> 16;
  b = (b + 0x7FFFu + ((b >> 16) & 1u)) >> 16;
  return a | (b << 16);
}

__global__ __launch_bounds__(256) void init_cursors(int* __restrict__ gcurA,
                                                    int* __restrict__ gcur2) {
  int i = blockIdx.x * 256 + threadIdx.x;
  if (i < NMB) gcurA[i] = i * MBCAP;
  if (i < NMB * 16) gcur2[i] = i * CAPF;
}

// pass A: chunk -> LDS counting sort by megabucket -> contiguous per-bin copy-out
__global__ __launch_bounds__(256) void partA(
    const int* __restrict__ src, const int* __restrict__ dst,
    int* __restrict__ gcurA, int* __restrict__ colA) {
  __shared__ int hist[NMB], base[NMB], lcur[NMB], excl[NMB];
  __shared__ int sc[128];
  __shared__ int sorted[CHUNK];  // 32 KB
  int t = threadIdx.x;
  for (int i = t; i < NMB; i += 256) hist[i] = 0;
  __syncthreads();
  int e0 = blockIdx.x * CHUNK;
  int cnt = N_EDGES - e0; if (cnt > CHUNK) cnt = CHUNK;
  for (int i = t; i < cnt; i += 256) atomicAdd(&hist[dst[e0 + i] >> MBSHIFT], 1);
  __syncthreads();
  if (t < 128) sc[t] = (t < NMB) ? hist[t] : 0;
  __syncthreads();
  for (int off = 1; off < 128; off <<= 1) {
    int v = (t < 128 && t >= off) ? sc[t - off] : 0;
    __syncthreads();
    if (t < 128) sc[t] += v;
    __syncthreads();
  }
  if (t < NMB) {
    int e = sc[t] - hist[t];
    excl[t] = e; lcur[t] = e;
    base[t] = hist[t] ? atomicAdd(&gcurA[t], hist[t]) : 0;
  }
  __syncthreads();
  for (int i = t; i < cnt; i += 256) {
    int d = dst[e0 + i];
    int b = d >> MBSHIFT;
    int r = atomicAdd(&lcur[b], 1);
    sorted[r] = (src[e0 + i] << MBSHIFT) | (d & 2047);
  }
  __syncthreads();
  for (int b = 0; b < NMB; b++) {
    int c = hist[b], gb = base[b], lb = excl[b];
    int lim = (b + 1) * MBCAP;
    for (int i = t; i < c; i += 256) {
      int pos = gb + i;
      if (pos < lim) colA[pos] = sorted[lb + i];  // 8-sigma guard
    }
  }
}

// pass B: megabucket chunk -> LDS sort into 16 fine buckets -> coalesced copy-out
__global__ __launch_bounds__(256) void partB(
    const int* __restrict__ gcurA, const int* __restrict__ colA,
    int* __restrict__ gcur2, int* __restrict__ col) {
  __shared__ int hist[16], base[16], lcur[16], excl[16];
  __shared__ int sorted[CHUNK];  // 32 KB
  int t = threadIdx.x;
  int mb = blockIdx.x / PB, j = blockIdx.x % PB;
  int mbbase = mb * MBCAP;
  int mbcnt = gcurA[mb] - mbbase; if (mbcnt > MBCAP) mbcnt = MBCAP;
  int c0 = j * CHUNK;
  int cnt = mbcnt - c0;
  if (cnt > CHUNK) cnt = CHUNK;
  if (cnt < 0) cnt = 0;
  if (t < 16) hist[t] = 0;
  __syncthreads();
  const int* seg = colA + mbbase + c0;
  for (int i = t; i < cnt; i += 256) atomicAdd(&hist[(seg[i] & 2047) >> FSHIFT], 1);
  __syncthreads();
  if (t == 0) {
    int run = 0;
    for (int b = 0; b < 16; b++) { excl[b] = run; lcur[b] = run; run += hist[b]; }
  }
  if (t < 16) base[t] = hist[t] ? atomicAdd(&gcur2[mb * 16 + t], hist[t]) : 0;
  __syncthreads();
  for (int i = t; i < cnt; i += 256) {
    int p = seg[i];
    int b = (p & 2047) >> FSHIFT;
    int r = atomicAdd(&lcur[b], 1);
    sorted[r] = ((p >> MBSHIFT) << FSHIFT) | (p & 127);  // src<<7 | dst&127
  }
  __syncthreads();
  for (int b = 0; b < 16; b++) {
    int c = hist[b], gb = base[b], lb = excl[b];
    int lim = (mb * 16 + b + 1) * CAPF;
    for (int i = t; i < c; i += 256) {
      int pos = gb + i;
      if (pos < lim) col[pos] = sorted[lb + i];  // 8-sigma guard
    }
  }
}

// fine sort: 128-bin counting sort fully staged in LDS, linear coalesced write-back
__global__ __launch_bounds__(256) void sort_fine(
    const int* __restrict__ gcur2, int* __restrict__ col,
    int* __restrict__ rowstart, int* __restrict__ rowcnt) {
  __shared__ int hist[128], sc[128], lcur[128];
  __shared__ int sorted[CAPF];   // 18 KB
  int t = threadIdx.x;
  int fb = blockIdx.x;
  int beg = fb * CAPF;
  int cnt = gcur2[fb] - beg; if (cnt > CAPF) cnt = CAPF;
  if (t < 128) hist[t] = 0;
  __syncthreads();
  for (int i = t; i < cnt; i += 256) atomicAdd(&hist[col[beg + i] & 127], 1);
  __syncthreads();
  if (t < 128) sc[t] = hist[t];
  __syncthreads();
  for (int off = 1; off < 128; off <<= 1) {
    int v = (t < 128 && t >= off) ? sc[t - off] : 0;
    __syncthreads();
    if (t < 128) sc[t] += v;
    __syncthreads();
  }
  if (t < 128) {
    int excl = sc[t] - hist[t];
    lcur[t] = excl;
    int n = fb * 128 + t;
    if (n < N_NODES) { rowstart[n] = beg + excl; rowcnt[n] = hist[t]; }
  }
  __syncthreads();
  for (int i = t; i < cnt; i += 256) {
    int p = col[beg + i];
    int r = atomicAdd(&lcur[p & 127], 1);
    sorted[r] = p >> FSHIFT;   // src only, grouped by dst
  }
  __syncthreads();
  for (int i = t; i < cnt; i += 256) col[beg + i] = sorted[i];
}

// ---------- layer 1 aggregation: one wave per node, dim 2 (x is f32) ----------
__global__ __launch_bounds__(256) void aggr2_wave(
    const int* __restrict__ rowstart, const int* __restrict__ rowcnt,
    const int* __restrict__ col, const float* __restrict__ x,
    float* __restrict__ agg) {
  int n = blockIdx.x * 4 + (threadIdx.x >> 6);  // 200000 = 50000*4 exactly
  int lane = threadIdx.x & 63;
  int e0 = rowstart[n], c = rowcnt[n];
  float a0 = 0.f, a1 = 0.f;
  for (int basei = 0; basei < c; basei += 64) {
    int idx = basei + lane;
    if (idx < c) {
      int s = col[e0 + idx];
      float2 u = *reinterpret_cast<const float2*>(x + 2 * s);
      a0 += u.x; a1 += u.y;
    }
  }
#pragma unroll
  for (int off = 1; off <= 32; off <<= 1) {
    a0 += __shfl_xor(a0, off, 64);
    a1 += __shfl_xor(a1, off, 64);
  }
  if (lane == 0) {
    *reinterpret_cast<float2*>(agg + 2 * n) = make_float2(a0, a1);
  }
}

// ---------- layers 2/3 aggregation: one wave per node, dim 16, bf16 gather ----------
// h row = 32 B = 2 uint4; lane pair splits the row (16 B each), f32 accumulate.
__global__ __launch_bounds__(256) void aggr16_wave(
    const int* __restrict__ rowstart, const int* __restrict__ rowcnt,
    const int* __restrict__ col, const uint4* __restrict__ hbf,
    float* __restrict__ agg) {
  int n = blockIdx.x * 4 + (threadIdx.x >> 6);
  int lane = threadIdx.x & 63;
  int e0 = rowstart[n], c = rowcnt[n];
  float a[8];
#pragma unroll
  for (int j = 0; j < 8; j++) a[j] = 0.f;
  int half = lane & 1;
  for (int basei = 0; basei < c; basei += 32) {
    int idx = basei + (lane >> 1);
    if (idx < c) {
      int s = col[e0 + idx];
      uint4 u = hbf[2 * s + half];   // 8 bf16 = 16 B
      a[0] += bf_lo(u.x); a[1] += bf_hi(u.x);
      a[2] += bf_lo(u.y); a[3] += bf_hi(u.y);
      a[4] += bf_lo(u.z); a[5] += bf_hi(u.z);
      a[6] += bf_lo(u.w); a[7] += bf_hi(u.w);
    }
  }
#pragma unroll
  for (int off = 2; off <= 32; off <<= 1) {
#pragma unroll
    for (int j = 0; j < 8; j++) a[j] += __shfl_xor(a[j], off, 64);
  }
  if (lane < 2) {
    float* dstp = agg + n * 16 + 8 * lane;
    *reinterpret_cast<float4*>(dstp) = make_float4(a[0], a[1], a[2], a[3]);
    *reinterpret_cast<float4*>(dstp + 4) = make_float4(a[4], a[5], a[6], a[7]);
  }
}

// ---------- layer 1 node MLP (2 -> 16 -> 16), outer relu, bf16 out ----------
__global__ __launch_bounds__(256) void node_l1(
    const float* __restrict__ x, const float* __restrict__ aggr,
    const float* __restrict__ Wa, const float* __restrict__ ba,
    const float* __restrict__ Wb, const float* __restrict__ bb,
    uint4* __restrict__ out) {
  __shared__ float sWa[32], sba[16], sWb[256], sbb[16];
  int t = threadIdx.x;
  if (t < 32) sWa[t] = Wa[t];
  if (t < 16) { sba[t] = ba[t]; sbb[t] = bb[t]; }
  for (int i = t; i < 256; i += 256) sWb[i] = Wb[i];
  __syncthreads();
  int n = blockIdx.x * blockDim.x + t;
  if (n >= N_NODES) return;
  float2 xv = *reinterpret_cast<const float2*>(x + 2 * n);
  float2 av = *reinterpret_cast<const float2*>(aggr + 2 * n);
  float v0 = xv.x + av.x, v1 = xv.y + av.y;
  float h1[16];
#pragma unroll
  for (int j = 0; j < 16; j++)
    h1[j] = fmaxf(fmaf(v0, sWa[j], fmaf(v1, sWa[16 + j], sba[j])), 0.f);
  float o[16];
#pragma unroll
  for (int j = 0; j < 16; j++) {
    float s = sbb[j];
#pragma unroll
    for (int k = 0; k < 16; k++) s = fmaf(h1[k], sWb[k * 16 + j], s);
    o[j] = fmaxf(s, 0.f);
  }
  out[2 * n]     = make_uint4(pack_bf2(o[0], o[1]),  pack_bf2(o[2], o[3]),
                              pack_bf2(o[4], o[5]),  pack_bf2(o[6], o[7]));
  out[2 * n + 1] = make_uint4(pack_bf2(o[8], o[9]),  pack_bf2(o[10], o[11]),
                              pack_bf2(o[12], o[13]), pack_bf2(o[14], o[15]));
}

// ---------- layers 2/3 node MLP (16 -> 16 -> 16), outer relu, bf16 in/out ----------
__global__ __launch_bounds__(256) void node16(
    const uint4* __restrict__ hin, const float* __restrict__ aggr,
    const float* __restrict__ Wa, const float* __restrict__ ba,
    const float* __restrict__ Wb, const float* __restrict__ bb,
    uint4* __restrict__ out) {
  __shared__ float sWa[256], sba[16], sWb[256], sbb[16];
  int t = threadIdx.x;
  if (t < 16) { sba[t] = ba[t]; sbb[t] = bb[t]; }
  for (int i = t; i < 256; i += 256) { sWa[i] = Wa[i]; sWb[i] = Wb[i]; }
  __syncthreads();
  int n = blockIdx.x * blockDim.x + t;
  if (n >= N_NODES) return;
  uint4 r0 = hin[2 * n], r1 = hin[2 * n + 1];
  const float4* ap = reinterpret_cast<const float4*>(aggr + 16 * n);
  float4 a0 = ap[0], a1 = ap[1], a2 = ap[2], a3 = ap[3];
  float v[16];
  v[0]  = bf_lo(r0.x) + a0.x;  v[1]  = bf_hi(r0.x) + a0.y;
  v[2]  = bf_lo(r0.y) + a0.z;  v[3]  = bf_hi(r0.y) + a0.w;
  v[4]  = bf_lo(r0.z) + a1.x;  v[5]  = bf_hi(r0.z) + a1.y;
  v[6]  = bf_lo(r0.w) + a1.z;  v[7]  = bf_hi(r0.w) + a1.w;
  v[8]  = bf_lo(r1.x) + a2.x;  v[9]  = bf_hi(r1.x) + a2.y;
  v[10] = bf_lo(r1.y) + a2.z;  v[11] = bf_hi(r1.y) + a2.w;
  v[12] = bf_lo(r1.z) + a3.x;  v[13] = bf_hi(r1.z) + a3.y;
  v[14] = bf_lo(r1.w) + a3.z;  v[15] = bf_hi(r1.w) + a3.w;
  float h1[16];
#pragma unroll
  for (int j = 0; j < 16; j++) {
    float s = sba[j];
#pragma unroll
    for (int k = 0; k < 16; k++) s = fmaf(v[k], sWa[k * 16 + j], s);
    h1[j] = fmaxf(s, 0.f);
  }
  float o[16];
#pragma unroll
  for (int j = 0; j < 16; j++) {
    float s = sbb[j];
#pragma unroll
    for (int k = 0; k < 16; k++) s = fmaf(h1[k], sWb[k * 16 + j], s);
    o[j] = fmaxf(s, 0.f);
  }
  out[2 * n]     = make_uint4(pack_bf2(o[0], o[1]),  pack_bf2(o[2], o[3]),
                              pack_bf2(o[4], o[5]),  pack_bf2(o[6], o[7]));
  out[2 * n + 1] = make_uint4(pack_bf2(o[8], o[9]),  pack_bf2(o[10], o[11]),
                              pack_bf2(o[12], o[13]), pack_bf2(o[14], o[15]));
}

// ---------- pool: one 64-lane block per graph; batch is sorted; bf16 input ----------
__global__ __launch_bounds__(64) void pool_kernel(
    const uint4* __restrict__ h, const int* __restrict__ batch,
    float* __restrict__ g) {
  int gr = blockIdx.x;
  int lo = 0, hi = N_NODES;
  while (lo < hi) { int mid = (lo + hi) >> 1; if (batch[mid] < gr) lo = mid + 1; else hi = mid; }
  int start = lo;
  hi = N_NODES;
  while (lo < hi) { int mid = (lo + hi) >> 1; if (batch[mid] < gr + 1) lo = mid + 1; else hi = mid; }
  int end = lo;
  float acc[16];
#pragma unroll
  for (int j = 0; j < 16; j++) acc[j] = 0.f;
  for (int n = start + threadIdx.x; n < end; n += 64) {
    uint4 r0 = h[2 * n], r1 = h[2 * n + 1];
    acc[0]  += bf_lo(r0.x); acc[1]  += bf_hi(r0.x);
    acc[2]  += bf_lo(r0.y); acc[3]  += bf_hi(r0.y);
    acc[4]  += bf_lo(r0.z); acc[5]  += bf_hi(r0.z);
    acc[6]  += bf_lo(r0.w); acc[7]  += bf_hi(r0.w);
    acc[8]  += bf_lo(r1.x); acc[9]  += bf_hi(r1.x);
    acc[10] += bf_lo(r1.y); acc[11] += bf_hi(r1.y);
    acc[12] += bf_lo(r1.z); acc[13] += bf_hi(r1.z);
    acc[14] += bf_lo(r1.w); acc[15] += bf_hi(r1.w);
  }
#pragma unroll
  for (int j = 0; j < 16; j++) {
#pragma unroll
    for (int off = 32; off > 0; off >>= 1) acc[j] += __shfl_xor(acc[j], off, 64);
  }
  if (threadIdx.x == 0) {
    float4* gp = reinterpret_cast<float4*>(g + gr * 16);
#pragma unroll
    for (int q = 0; q < 4; q++)
      gp[q] = make_float4(acc[4 * q], acc[4 * q + 1], acc[4 * q + 2], acc[4 * q + 3]);
  }
}

// ---------- head: relu(g@Wl1+bl1)@Wl2+bl2 ----------
__global__ __launch_bounds__(256) void head_kernel(
    const float* __restrict__ g,
    const float* __restrict__ Wl1, const float* __restrict__ bl1,
    const float* __restrict__ Wl2, const float* __restrict__ bl2,
    float* __restrict__ out) {
  __shared__ float sW1[256], sb1[16], sW2[16];
  int t = threadIdx.x;
  if (t < 16) { sb1[t] = bl1[t]; sW2[t] = Wl2[t]; }
  for (int i = t; i < 256; i += 256) sW1[i] = Wl1[i];
  __syncthreads();
  int gr = blockIdx.x * blockDim.x + t;
  if (gr >= N_GRAPHS) return;
  float v[16];
  const float4* gp = reinterpret_cast<const float4*>(g + 16 * gr);
#pragma unroll
  for (int q = 0; q < 4; q++) {
    float4 gv = gp[q];
    v[4 * q + 0] = gv.x; v[4 * q + 1] = gv.y; v[4 * q + 2] = gv.z; v[4 * q + 3] = gv.w;
  }
  float o = bl2[0];
#pragma unroll
  for (int j = 0; j < 16; j++) {
    float s = sb1[j];
#pragma unroll
    for (int k = 0; k < 16; k++) s = fmaf(v[k], sW1[k * 16 + j], s);
    o = fmaf(fmaxf(s, 0.f), sW2[j], o);
  }
  out[gr] = o;
}

extern "C" void kernel_launch(void* const* d_in, const int* in_sizes, int n_in,
                              void* d_out, int out_size, void* d_ws, size_t ws_size,
                              hipStream_t stream) {
  const float* x     = (const float*)d_in[0];
  const int*   ei    = (const int*)d_in[1];
  const int*   src   = ei;
  const int*   dst   = ei + N_EDGES;
  const int*   batch = (const int*)d_in[2];
  const float* W1a = (const float*)d_in[3];  const float* b1a = (const float*)d_in[4];
  const float* W1b = (const float*)d_in[5];  const float* b1b = (const float*)d_in[6];
  const float* W2a = (const float*)d_in[7];  const float* b2a = (const float*)d_in[8];
  const float* W2b = (const float*)d_in[9];  const float* b2b = (const float*)d_in[10];
  const float* W3a = (const float*)d_in[11]; const float* b3a = (const float*)d_in[12];
  const float* W3b = (const float*)d_in[13]; const float* b3b = (const float*)d_in[14];
  const float* Wl1 = (const float*)d_in[15]; const float* bl1 = (const float*)d_in[16];
  const float* Wl2 = (const float*)d_in[17]; const float* bl2 = (const float*)d_in[18];
  float* out = (float*)d_out;

  // ws layout (ints). colA aliases the layer-buffer region (dead after partB).
  int*   gcurA    = (int*)d_ws;                         // NMB (pad 128)
  int*   gcur2    = gcurA + 128;                        // NMB*16=1568 (pad 2048)
  int*   rowstart = gcur2 + 2048;                       // N_NODES (pad 200192)
  int*   rowcnt   = rowstart + 200192;                  // N_NODES (pad 200192)
  int*   col      = rowcnt + 200192;                    // NBUCK*CAPF = 7,202,304
  int*   U        = col + (size_t)NBUCK * CAPF;         // union region (6,623,232 ints)
  int*   colA     = U;                                  // NMB*MBCAP ints
  float* agg      = (float*)U;                          // N_NODES*16 f32 (3.2M ints)
  uint4* hA       = (uint4*)(agg + (size_t)N_NODES * 16);   // N_NODES*32B bf16
  uint4* hB       = hA + (size_t)N_NODES * 2;               // N_NODES*32B bf16
  float* g        = (float*)(hB + (size_t)N_NODES * 2);     // N_GRAPHS*16
  // total U usage: 3.2M + 1.6M + 1.6M + 32K ints = 6.43M < 6.62M ✓

  const int NWAVE_BLK = N_NODES / 4;                    // 50000 (exact)
  dim3 ngrid((N_NODES + 255) / 256);

  init_cursors<<<(NMB * 16 + 255) / 256, 256, 0, stream>>>(gcurA, gcur2);
  partA<<<PBLK, 256, 0, stream>>>(src, dst, gcurA, colA);
  partB<<<NMB * PB, 256, 0, stream>>>(gcurA, colA, gcur2, col);
  sort_fine<<<NBUCK, 256, 0, stream>>>(gcur2, col, rowstart, rowcnt);

  // layer 1
  aggr2_wave<<<NWAVE_BLK, 256, 0, stream>>>(rowstart, rowcnt, col, x, agg);
  node_l1<<<ngrid, 256, 0, stream>>>(x, agg, W1a, b1a, W1b, b1b, hA);
  // layer 2
  aggr16_wave<<<NWAVE_BLK, 256, 0, stream>>>(rowstart, rowcnt, col, hA, agg);
  node16<<<ngrid, 256, 0, stream>>>(hA, agg, W2a, b2a, W2b, b2b, hB);
  // layer 3
  aggr16_wave<<<NWAVE_BLK, 256, 0, stream>>>(rowstart, rowcnt, col, hB, agg);
  node16<<<ngrid, 256, 0, stream>>>(hB, agg, W3a, b3a, W3b, b3b, hA);

  pool_kernel<<<N_GRAPHS, 64, 0, stream>>>(hA, batch, g);
  head_kernel<<<(N_GRAPHS + 255) / 256, 256, 0, stream>>>(g, Wl1, bl1, Wl2, bl2, out);
}